// Round 15
// baseline (483.954 us; speedup 1.0000x reference)
//
#include <hip/hip_runtime.h>
#include <hip/hip_bf16.h>
#include <cstdint>
#include <cstddef>

#define NN    6720     // nodes
#define MPAD  6912     // 27 * 256 = 54 * 128
#define NE    33600    // edges
#define KDIM  2048
#define HC1   2048
#define EAP   2100     // edge_attr tile period

typedef __attribute__((ext_vector_type(8))) short bhalf8;
typedef __attribute__((ext_vector_type(4))) short bhalf4;
typedef __attribute__((ext_vector_type(4))) float fx4;

__device__ __forceinline__ float bf2f(short s) {
    union { unsigned int u; float f; } c;
    c.u = ((unsigned int)(unsigned short)s) << 16;
    return c.f;
}

__device__ __forceinline__ void gload16(const __hip_bfloat16* g, void* lds)
{
    __builtin_amdgcn_global_load_lds(
        (const __attribute__((address_space(1))) unsigned int*)g,
        (__attribute__((address_space(3))) unsigned int*)lds,
        16, 0, 0);
}

#define CFENCE asm volatile("" ::: "memory")

// ------------------------------------------------------------------
// 256x256-block 4-wave fused projection GEMM, SQUARE 128x128 wave
// tile (acc[8][8] = 256 VGPR). Rationale: LDS reads/FLOP drop from
// 12/32-MFMA (0.375) to 16/64-MFMA (0.25); per-CU LDS pipe ~768 cyc
// vs matrix ~2480 cyc -> matrix-bound ceiling (~70%) instead of the
// ~50% LDS/matrix 1:1 ceiling of the 128x64 wave tile. 1 block/CU
// (96KB LDS ring, 4 waves, 1/SIMD) - relies on in-wave ILP.
// BK=32, 3-deep ring, counted vmcnt(16/8/0), XOR swizzle both-sides,
// XCD stripe (XCD owns 4 N-panels of 256 = 4MB = L2).
// Epilogue: 272B-padded LDS scratch, uniform bf16 full-line stores.
// ------------------------------------------------------------------
__global__ __launch_bounds__(256) void gemm256sq_fused(
    const __hip_bfloat16* __restrict__ A,
    const __hip_bfloat16* __restrict__ Bt,
    const float* __restrict__ bcat,
    __hip_bfloat16* __restrict__ oq,
    __hip_bfloat16* __restrict__ ok,
    __hip_bfloat16* __restrict__ ov,
    __hip_bfloat16* __restrict__ oh)
{
    __shared__ alignas(16) char Lds[98304];   // A ring 3x16KB @0 | B ring 3x16KB @49152

    const int bid = blockIdx.x;
    const int i0  = bid >> 3;
    const int bx  = (bid & 7) * 4 + (i0 & 3);   // 32 N-panels of 256
    const int by  = i0 >> 2;                    // 27 M-panels of 256

    const int tid  = threadIdx.x;
    const int w    = tid >> 6;        // 0..3
    const int lane = tid & 63;
    const int wm = w >> 1, wnn = w & 1;   // 2x2 waves, wave tile 128x128
    const int rowA = by * 256;
    const int rowB = bx * 256;

    // staging: wave w covers rows w*64..+63 of each 256x32 plane
    // (4 gload16 per plane). Pre-swizzled source (64B LDS rows,
    // unit ^= (row>>1)&3).
    const int sug = ((lane & 3) ^ ((lane >> 3) & 3)) << 3;
    const __hip_bfloat16* Ag0 = A  + (size_t)(rowA + w * 64 + (lane >> 2)) * KDIM + sug;
    const __hip_bfloat16* Bg0 = Bt + (size_t)(rowB + w * 64 + (lane >> 2)) * KDIM + sug;

    const int rds = (((lane >> 4) ^ (((lane & 15) >> 1) & 3)) << 4);

    fx4 acc[8][8] = {};

#define STAGE(T)                                                          \
    { const int s_ = (T) % 3; const int k0_ = (T) * 32;                   \
      char* ab_ = Lds + s_ * 16384 + w * 4096;                            \
      char* bb_ = Lds + 49152 + s_ * 16384 + w * 4096;                    \
      gload16(Ag0 + k0_, ab_);                                            \
      gload16(Ag0 + k0_ + 16 * KDIM, ab_ + 1024);                         \
      gload16(Ag0 + k0_ + 32 * KDIM, ab_ + 2048);                         \
      gload16(Ag0 + k0_ + 48 * KDIM, ab_ + 3072);                         \
      gload16(Bg0 + k0_, bb_);                                            \
      gload16(Bg0 + k0_ + 16 * KDIM, bb_ + 1024);                         \
      gload16(Bg0 + k0_ + 32 * KDIM, bb_ + 2048);                         \
      gload16(Bg0 + k0_ + 48 * KDIM, bb_ + 3072); }

#define TILE(T, VM, DOSTAGE)                                              \
    { if (DOSTAGE) { STAGE((T) + 2); }                                    \
      asm volatile("s_waitcnt vmcnt(" VM ")" ::: "memory");               \
      __builtin_amdgcn_s_barrier(); CFENCE;                               \
      const int s_ = (T) % 3;                                             \
      const char* ap_ = Lds + s_ * 16384;                                 \
      const char* bp_ = Lds + 49152 + s_ * 16384;                         \
      bhalf8 af_[8], bf_[8];                                              \
      _Pragma("unroll")                                                   \
      for (int nj = 0; nj < 8; ++nj)                                      \
          bf_[nj] = *(const bhalf8*)(bp_ + (wnn * 128 + nj * 16 + (lane & 15)) * 64 + rds); \
      _Pragma("unroll")                                                   \
      for (int mi = 0; mi < 8; ++mi)                                      \
          af_[mi] = *(const bhalf8*)(ap_ + (wm * 128 + mi * 16 + (lane & 15)) * 64 + rds); \
      __builtin_amdgcn_s_setprio(1);                                      \
      _Pragma("unroll")                                                   \
      for (int mi = 0; mi < 8; ++mi)                                      \
          _Pragma("unroll")                                               \
          for (int nj = 0; nj < 8; ++nj)                                  \
              acc[mi][nj] = __builtin_amdgcn_mfma_f32_16x16x32_bf16(      \
                  af_[mi], bf_[nj], acc[mi][nj], 0, 0, 0);                \
      __builtin_amdgcn_s_setprio(0); CFENCE;                              \
      __builtin_amdgcn_s_barrier(); CFENCE; }

    STAGE(0); STAGE(1);
    for (int t = 0; t < (KDIM / 32) - 2; ++t) {
        TILE(t, "16", 1);
    }
    TILE((KDIM / 32) - 2, "8", 0);
    TILE((KDIM / 32) - 1, "0", 0);

#undef TILE
#undef STAGE

    // ---- epilogue: 272B-padded LDS scratch, uniform bf16 stores ----
    const int gcol = rowB + wnn * 128;
    const int seg  = gcol >> 11;            // 0:q 1:k 2:v 3:skip
    const int lcol = gcol & 2047;
    float bv[8];
    #pragma unroll
    for (int nj = 0; nj < 8; ++nj) bv[nj] = bcat[gcol + nj * 16 + (lane & 15)];
    char* scr = Lds + w * 8704;             // wave-private 32 rows x 272B
    const int growA = rowA + wm * 128;
    __hip_bfloat16* dst = (seg == 0) ? oq : (seg == 1) ? ok : (seg == 2) ? ov : oh;

    #pragma unroll
    for (int c = 0; c < 4; ++c) {           // 4 row-chunks of 32
        #pragma unroll
        for (int nh = 0; nh < 2; ++nh) {    // 2 col-halves of 64
            #pragma unroll
            for (int m2 = 0; m2 < 2; ++m2) {
                const int mi = c * 2 + m2;
                #pragma unroll
                for (int njl = 0; njl < 4; ++njl) {
                    const int nj = nh * 4 + njl;
                    const int cl = njl * 16 + (lane & 15);
                    #pragma unroll
                    for (int i2 = 0; i2 < 4; ++i2) {
                        const int rl = m2 * 16 + ((lane >> 4) << 2) + i2;
                        *(float*)(scr + rl * 272 + cl * 4) = acc[mi][nj][i2] + bv[nj];
                    }
                }
            }
            asm volatile("s_waitcnt lgkmcnt(0)" ::: "memory");
            CFENCE;
            const int rrow = (lane >> 4);
            const int u    = lane & 15;
            #pragma unroll
            for (int p = 0; p < 8; ++p) {
                const int row = p * 4 + rrow;
                const float4 f = *(const float4*)(scr + row * 272 + u * 16);
                bhalf4 tb;
                tb[0] = (short)__bfloat16_as_ushort(__float2bfloat16(f.x));
                tb[1] = (short)__bfloat16_as_ushort(__float2bfloat16(f.y));
                tb[2] = (short)__bfloat16_as_ushort(__float2bfloat16(f.z));
                tb[3] = (short)__bfloat16_as_ushort(__float2bfloat16(f.w));
                *(bhalf4*)&dst[(size_t)(growA + c * 32 + row) * 2048
                               + lcol + nh * 64 + u * 4] = tb;
            }
            asm volatile("s_waitcnt lgkmcnt(0)" ::: "memory");
            CFENCE;
        }
    }
}

// ------------------------------------------------------------------
// 128x128 bf16 MFMA GEMM (4 waves), optional split-K via blockIdx.z.
// flags: 1=+bias  2=+=C fp32 read  4=relu  8=skip C writeback
//        16=+=Cb bf16 read (in-place bf16 accumulate path)
// ------------------------------------------------------------------
__global__ __launch_bounds__(256) void gemm_bf16(
    const __hip_bfloat16* __restrict__ A,
    const __hip_bfloat16* __restrict__ Bt,
    const float* __restrict__ bias,
    float* __restrict__ C,
    __hip_bfloat16* __restrict__ Cb,
    int M, int N, int K, int flags)
{
    __shared__ alignas(16) __hip_bfloat16 Asm[128 * 64];
    __shared__ alignas(16) __hip_bfloat16 Bsm[128 * 64];
    const int tid  = threadIdx.x;
    const int w    = tid >> 6;
    const int lane = tid & 63;
    const int wr = w >> 1, wc = w & 1;
    const int rowA = blockIdx.y * 128;
    const int rowB = blockIdx.x * 128;
    const int klen = K / gridDim.z;
    const int kbeg = blockIdx.z * klen;

    const int srow = w * 32 + (lane >> 3);
    const int ug8  = ((lane & 7) ^ (lane >> 3)) << 3;
    const __hip_bfloat16* Ag = A  + (size_t)(rowA + srow) * K + ug8;
    const __hip_bfloat16* Bg = Bt + (size_t)(rowB + srow) * K + ug8;
    char* AsBase = (char*)Asm + w * 4096;
    char* BsBase = (char*)Bsm + w * 4096;

    fx4 acc[4][4] = {};

    const int fra = wr * 64 + (lane & 15);
    const int frb = wc * 64 + (lane & 15);
    const int kb  = (lane >> 4) << 4;
    const int swz = (lane & 7) << 4;

    for (int k0 = kbeg; k0 < kbeg + klen; k0 += 64) {
        __syncthreads();
        #pragma unroll
        for (int j = 0; j < 4; ++j) {
            gload16(Ag + (size_t)j * 8 * K + k0, AsBase + j * 1024);
            gload16(Bg + (size_t)j * 8 * K + k0, BsBase + j * 1024);
        }
        __syncthreads();
        #pragma unroll
        for (int kk = 0; kk < 2; ++kk) {
            const int cb = kk * 64 + kb;
            bhalf8 af[4], bfr[4];
            #pragma unroll
            for (int mi = 0; mi < 4; ++mi)
                af[mi] = *(const bhalf8*)((const char*)Asm + (fra + mi * 16) * 128 + (cb ^ swz));
            #pragma unroll
            for (int nj = 0; nj < 4; ++nj)
                bfr[nj] = *(const bhalf8*)((const char*)Bsm + (frb + nj * 16) * 128 + (cb ^ swz));
            #pragma unroll
            for (int mi = 0; mi < 4; ++mi)
                #pragma unroll
                for (int nj = 0; nj < 4; ++nj)
                    acc[mi][nj] = __builtin_amdgcn_mfma_f32_16x16x32_bf16(
                        af[mi], bfr[nj], acc[mi][nj], 0, 0, 0);
        }
    }

    float* Cz = C ? C + (size_t)blockIdx.z * ((size_t)M * N) : nullptr;
    #pragma unroll
    for (int nj = 0; nj < 4; ++nj) {
        const int ccol = rowB + wc * 64 + nj * 16 + (lane & 15);
        const float bv = (flags & 1) ? bias[ccol] : 0.f;
        #pragma unroll
        for (int mi = 0; mi < 4; ++mi) {
            const int crow0 = rowA + wr * 64 + mi * 16 + ((lane >> 4) << 2);
            #pragma unroll
            for (int i = 0; i < 4; ++i) {
                size_t idx = (size_t)(crow0 + i) * N + ccol;
                float v = acc[mi][nj][i] + bv;
                if (flags & 2)  v += Cz[idx];
                if (flags & 16) v += __bfloat162float(Cb[idx]);
                if (flags & 4)  v = fmaxf(v, 0.f);
                if (Cz && !(flags & 8)) Cz[idx] = v;
                if (Cb) Cb[idx] = __float2bfloat16(v);
            }
        }
    }
}

// dst[i] = sum_z parts[z*stride + i] (+ bias[i & colmask])
__global__ void reduce4(const float* __restrict__ parts, size_t stride,
                        const float* __restrict__ bias, int colmask,
                        float* __restrict__ dst, int n)
{
    int i = blockIdx.x * 256 + threadIdx.x;
    if (i >= n) return;
    float v = parts[i] + parts[stride + i] + parts[2 * stride + i] + parts[3 * stride + i];
    if (bias) v += bias[i & colmask];
    dst[i] = v;
}

// ------------------------------------------------------------------
// CSR build
// ------------------------------------------------------------------
__global__ void count_deg(const int* __restrict__ ei, int* __restrict__ deg)
{
    int e = blockIdx.x * 256 + threadIdx.x;
    if (e < NE) atomicAdd(&deg[ei[NE + e]], 1);
}

__global__ __launch_bounds__(1024) void scan_kernel(const int* __restrict__ deg,
                                                    int* __restrict__ rowptr)
{
    __shared__ int s[1024];
    const int t = threadIdx.x;
    const int base = t * 7;
    int loc[7];
    int sum = 0;
    #pragma unroll
    for (int i = 0; i < 7; ++i) {
        int idx = base + i;
        int v = (idx < NN) ? deg[idx] : 0;
        loc[i] = v; sum += v;
    }
    s[t] = sum;
    __syncthreads();
    for (int off = 1; off < 1024; off <<= 1) {
        int v = (t >= off) ? s[t - off] : 0;
        __syncthreads();
        s[t] += v;
        __syncthreads();
    }
    int running = s[t] - sum;
    #pragma unroll
    for (int i = 0; i < 7; ++i) {
        int idx = base + i;
        if (idx <= NN) rowptr[idx] = running;
        if (idx < NN) running += loc[i];
    }
}

__global__ void fill_csr(const int* __restrict__ ei, const int* __restrict__ rowptr,
                         int* __restrict__ fillctr, int* __restrict__ elist)
{
    int e = blockIdx.x * 256 + threadIdx.x;
    if (e >= NE) return;
    int d = ei[NE + e];
    int pos = atomicAdd(&fillctr[d], 1);
    elist[rowptr[d] + pos] = e;
}

__global__ void sort_csr(const int* __restrict__ rowptr, int* __restrict__ elist)
{
    int n = blockIdx.x * 256 + threadIdx.x;
    if (n >= NN) return;
    int s0 = rowptr[n], s1 = rowptr[n + 1];
    for (int i = s0 + 1; i < s1; ++i) {
        int v = elist[i];
        int j = i - 1;
        while (j >= s0 && elist[j] > v) { elist[j + 1] = elist[j]; --j; }
        elist[j + 1] = v;
    }
}

// ------------------------------------------------------------------
// merged prep kernel: roles by block range.
//  [0,6912)            cvt_pad: x -> xb bf16 (zero pad rows)
//  [6912,23296)        transpose_cvt4: wcat[z] = Wz^T bf16
//  [23296,27424)       build_misc: bcat | w1pp | w1ppT | w2t+b2
//  [27424,27457)       E2s = ea[0:2112] @ e2w (fp32 64x64 tile gemm)
// ------------------------------------------------------------------
__global__ __launch_bounds__(256) void prep_kernel(
    const float* __restrict__ x, __hip_bfloat16* __restrict__ xb,
    const float* __restrict__ q1w, const float* __restrict__ k1w,
    const float* __restrict__ v1w, const float* __restrict__ s1w,
    __hip_bfloat16* __restrict__ wcat,
    const float* __restrict__ q1b, const float* __restrict__ k1b,
    const float* __restrict__ v1b, const float* __restrict__ s1b,
    const float* __restrict__ e1w,
    const float* __restrict__ q2w, const float* __restrict__ k2w,
    const float* __restrict__ v2w, const float* __restrict__ s2w,
    const float* __restrict__ q2bb, const float* __restrict__ k2bb,
    const float* __restrict__ v2bb, const float* __restrict__ s2bb,
    float* __restrict__ bcat, __hip_bfloat16* __restrict__ w1pp,
    __hip_bfloat16* __restrict__ w1ppT, __hip_bfloat16* __restrict__ w2t,
    float* __restrict__ b2,
    const float* __restrict__ ea, const float* __restrict__ e2w,
    float* __restrict__ E2s)
{
    __shared__ alignas(16) char plds[8448];
    const int bid = blockIdx.x;
    const int tid = threadIdx.x;

    if (bid < 6912) {                       // ---- cvt_pad (1 row/block) ----
        const int row = bid;
        const size_t base = (size_t)row * KDIM + tid * 8;
        float4 v0 = make_float4(0.f, 0.f, 0.f, 0.f), v1 = v0;
        if (row < NN) {
            v0 = *(const float4*)&x[base];
            v1 = *(const float4*)&x[base + 4];
        }
        bhalf8 o;
        o[0] = (short)__bfloat16_as_ushort(__float2bfloat16(v0.x));
        o[1] = (short)__bfloat16_as_ushort(__float2bfloat16(v0.y));
        o[2] = (short)__bfloat16_as_ushort(__float2bfloat16(v0.z));
        o[3] = (short)__bfloat16_as_ushort(__float2bfloat16(v0.w));
        o[4] = (short)__bfloat16_as_ushort(__float2bfloat16(v1.x));
        o[5] = (short)__bfloat16_as_ushort(__float2bfloat16(v1.y));
        o[6] = (short)__bfloat16_as_ushort(__float2bfloat16(v1.z));
        o[7] = (short)__bfloat16_as_ushort(__float2bfloat16(v1.w));
        *(bhalf8*)&xb[base] = o;
        return;
    }
    if (bid < 23296) {                      // ---- transpose_cvt4 ----
        const int idx = bid - 6912;
        const int z   = idx >> 12;          // 0..3
        const int rem = idx & 4095;
        const int byi = rem >> 6, bxi = rem & 63;
        const float* W = (z == 0) ? q1w : (z == 1) ? k1w : (z == 2) ? v1w : s1w;
        __hip_bfloat16* Bt = wcat + (size_t)z * KDIM * KDIM;
        float (*t)[33] = (float (*)[33])plds;
        const int kb = byi * 32, nb = bxi * 32;
        const int tx = tid & 31, ty = tid >> 5;
        #pragma unroll
        for (int i = 0; i < 32; i += 8)
            t[ty + i][tx] = W[(size_t)(kb + ty + i) * KDIM + nb + tx];
        __syncthreads();
        #pragma unroll
        for (int i = 0; i < 32; i += 8)
            Bt[(size_t)(nb + ty + i) * KDIM + kb + tx] = __float2bfloat16(t[tx][ty + i]);
        return;
    }
    if (bid < 27424) {                      // ---- build_misc ----
        int idx = (bid - 23296) * 256 + tid;
        if (idx < 8192) {
            int seg = idx >> 11, j = idx & 2047;
            const float* b = (seg == 0) ? q1b : (seg == 1) ? k1b : (seg == 2) ? v1b : s1b;
            bcat[idx] = b[j];
            return;
        }
        idx -= 8192;
        if (idx < 262144) {   // w1pp [128][2048]
            int p = idx >> 11, j = idx & 2047;
            float v = ((j >> 10) == (p >> 6)) ? e1w[(size_t)(p & 63) * KDIM + j] : 0.f;
            w1pp[idx] = __float2bfloat16(v);
            return;
        }
        idx -= 262144;
        if (idx < 262144) {   // w1ppT [2048][128]
            int n = idx >> 7, k = idx & 127;
            float v = ((n >> 10) == (k >> 6)) ? e1w[(size_t)(k & 63) * KDIM + n] : 0.f;
            w1ppT[idx] = __float2bfloat16(v);
            return;
        }
        idx -= 262144;        // w2t [256][2048] + b2
        int c = idx >> 11, d = idx & 2047;
        int g = c >> 6, j = c & 63;
        const float* w = (g == 0) ? q2w : (g == 1) ? k2w : (g == 2) ? v2w : s2w;
        w2t[idx] = __float2bfloat16(w[(size_t)d * 64 + j]);
        if (d == 0) {
            const float* b = (g == 0) ? q2bb : (g == 1) ? k2bb : (g == 2) ? v2bb : s2bb;
            b2[c] = b[j];
        }
        return;
    }
    // ---- E2s gemm: 64x64 tile, M=2112 N=64 K=64, by = bid-27424 ----
    {
        const int byi = bid - 27424;
        float (*As)[68] = (float (*)[68])plds;                 // 16x68 fp32
        float (*Bs)[64] = (float (*)[64])(plds + 4352);        // 16x64 fp32
        const int tx = tid & 15, ty = tid >> 4;
        const int arow = tid >> 2, acol = (tid & 3) << 2;
        const int brow = tid >> 4, bcol = (tid & 15) << 2;
        const float* Ag = ea + (size_t)(byi * 64 + arow) * 64 + acol;
        const float* Bg = e2w + (size_t)brow * 64 + bcol;
        float acc[4][4] = {};
        for (int k0 = 0; k0 < 64; k0 += 16) {
            const float4 av = *(const float4*)(Ag + k0);
            const float4 bv = *(const float4*)(Bg + (size_t)k0 * 64);
            __syncthreads();
            As[acol + 0][arow] = av.x;
            As[acol + 1][arow] = av.y;
            As[acol + 2][arow] = av.z;
            As[acol + 3][arow] = av.w;
            *(float4*)&Bs[brow][bcol] = bv;
            __syncthreads();
            #pragma unroll
            for (int kk = 0; kk < 16; ++kk) {
                const float4 a4 = *(const float4*)&As[kk][ty << 2];
                const float4 b4 = *(const float4*)&Bs[kk][tx << 2];
                const float a[4] = {a4.x, a4.y, a4.z, a4.w};
                const float b[4] = {b4.x, b4.y, b4.z, b4.w};
                #pragma unroll
                for (int i = 0; i < 4; ++i)
                    #pragma unroll
                    for (int j = 0; j < 4; ++j)
                        acc[i][j] += a[i] * b[j];
            }
        }
        const int crow = byi * 64 + (ty << 2);
        const int ccol = (tx << 2);
        #pragma unroll
        for (int i = 0; i < 4; ++i) {
            float4 v;
            v.x = acc[i][0]; v.y = acc[i][1]; v.z = acc[i][2]; v.w = acc[i][3];
            *(float4*)&E2s[(size_t)(crow + i) * 64 + ccol] = v;
        }
    }
}

// ------------------------------------------------------------------
// node1: fused alpha1 + softmax + R1 + V-aggregation. One block/node.
// ------------------------------------------------------------------
__global__ __launch_bounds__(256) void node1_kernel(
    const __hip_bfloat16* __restrict__ q1b, const __hip_bfloat16* __restrict__ k1b,
    const __hip_bfloat16* __restrict__ v1b,
    const float* __restrict__ P1, const float* __restrict__ ea,
    const int* __restrict__ ei, const int* __restrict__ rowptr,
    const int* __restrict__ elist,
    __hip_bfloat16* __restrict__ h1, __hip_bfloat16* __restrict__ R1)
{
    __shared__ int   s_src[256];
    __shared__ int   s_em[256];
    __shared__ float s_at[256][2];
    const int n = blockIdx.x;
    const int s0 = rowptr[n];
    const int deg = rowptr[n + 1] - s0;
    const int w = threadIdx.x >> 6, lane = threadIdx.x & 63;

    for (int j = w; j < deg; j += 4) {
        const int e = elist[s0 + j];
        const int src = ei[e];
        const int em = e % EAP;
        if (lane == 0) { s_src[j] = src; s_em[j] = em; }
        const float eaj = ea[(size_t)em * 64 + lane];
        #pragma unroll
        for (int h = 0; h < 2; ++h) {
            const __hip_bfloat16* qh = q1b + (size_t)n * HC1 + h * 1024 + lane * 16;
            const __hip_bfloat16* kh = k1b + (size_t)src * HC1 + h * 1024 + lane * 16;
            bhalf8 qa = *(const bhalf8*)qh, qc = *(const bhalf8*)(qh + 8);
            bhalf8 ka = *(const bhalf8*)kh, kc = *(const bhalf8*)(kh + 8);
            float s = 0.f;
            #pragma unroll
            for (int jj = 0; jj < 8; ++jj) s += bf2f(qa[jj]) * bf2f(ka[jj]);
            #pragma unroll
            for (int jj = 0; jj < 8; ++jj) s += bf2f(qc[jj]) * bf2f(kc[jj]);
            s += eaj * P1[(size_t)n * 128 + h * 64 + lane];
            #pragma unroll
            for (int off = 32; off; off >>= 1) s += __shfl_xor(s, off);
            if (lane == 0) s_at[j][h] = s * 0.03125f;
        }
    }
    __syncthreads();

    if (threadIdx.x < 2) {
        const int h = threadIdx.x;
        float m = -1e30f;
        for (int j = 0; j < deg; ++j) m = fmaxf(m, s_at[j][h]);
        float sum = 0.f;
        for (int j = 0; j < deg; ++j) {
            float ex = __expf(s_at[j][h] - m);
            s_at[j][h] = ex; sum += ex;
        }
        float inv = 1.f / (sum + 1e-16f);
        for (int j = 0; j < deg; ++j) s_at[j][h] *= inv;
    }
    __syncthreads();

    if (threadIdx.x < 128) {
        const int h = threadIdx.x >> 6, jj = threadIdx.x & 63;
        float r = 0.f;
        for (int j = 0; j < deg; ++j)
            r += s_at[j][h] * ea[(size_t)s_em[j] * 64 + jj];
        R1[(size_t)n * 128 + threadIdx.x] = __float2bfloat16(r);
    }

    const int c0 = threadIdx.x * 8;
    const int h = c0 >> 10;
    float acc[8];
    const bhalf8 cur = *(const bhalf8*)&h1[(size_t)n * HC1 + c0];
    #pragma unroll
    for (int jj = 0; jj < 8; ++jj) acc[jj] = bf2f(cur[jj]);
    for (int j = 0; j < deg; ++j) {
        const float at = s_at[j][h];
        bhalf8 v = *(const bhalf8*)&v1b[(size_t)s_src[j] * HC1 + c0];
        #pragma unroll
        for (int jj = 0; jj < 8; ++jj) acc[jj] += at * bf2f(v[jj]);
    }
    bhalf8 o;
    #pragma unroll
    for (int jj = 0; jj < 8; ++jj)
        o[jj] = (short)__bfloat16_as_ushort(__float2bfloat16(acc[jj]));
    *(bhalf8*)&h1[(size_t)n * HC1 + c0] = o;
}

// ------------------------------------------------------------------
// node2: fused alpha2 + softmax + aggregation + relu. 1 wave/node.
// ------------------------------------------------------------------
__global__ __launch_bounds__(64) void node2_kernel(
    const float* __restrict__ qkvs2, const float* __restrict__ E2s,
    const int* __restrict__ ei, const int* __restrict__ rowptr,
    const int* __restrict__ elist, float* __restrict__ out)
{
    __shared__ float s_at[256];
    __shared__ int   s_src[256];
    __shared__ int   s_em[256];
    const int n = blockIdx.x;
    const int s0 = rowptr[n];
    const int deg = rowptr[n + 1] - s0;
    const int c = threadIdx.x;
    const float q = qkvs2[(size_t)n * 256 + c];

    for (int j = 0; j < deg; ++j) {
        const int e = elist[s0 + j];
        const int src = ei[e];
        const int em = e % EAP;
        float s = q * (qkvs2[(size_t)src * 256 + 64 + c] + E2s[(size_t)em * 64 + c]);
        #pragma unroll
        for (int off = 32; off; off >>= 1) s += __shfl_xor(s, off);
        if (c == 0) { s_at[j] = s * 0.125f; s_src[j] = src; s_em[j] = em; }
    }
    __syncthreads();
    float m = -1e30f;
    for (int j = 0; j < deg; ++j) m = fmaxf(m, s_at[j]);
    float sum = 0.f;
    for (int j = 0; j < deg; ++j) sum += __expf(s_at[j] - m);
    const float inv = 1.f / (sum + 1e-16f);

    float acc = qkvs2[(size_t)n * 256 + 192 + c];
    for (int j = 0; j < deg; ++j) {
        const float at = __expf(s_at[j] - m) * inv;
        acc += at * (qkvs2[(size_t)s_src[j] * 256 + 128 + c] + E2s[(size_t)s_em[j] * 64 + c]);
    }
    out[(size_t)n * 64 + c] = fmaxf(acc, 0.f);
}

// ------------------------------------------------------------------
extern "C" void kernel_launch(void* const* d_in, const int* in_sizes, int n_in,
                              void* d_out, int out_size, void* d_ws, size_t ws_size,
                              hipStream_t stream)
{
    const float* x   = (const float*)d_in[0];
    const int*   ei  = (const int*)d_in[1];
    const float* ea  = (const float*)d_in[2];
    const float* q1w = (const float*)d_in[3];
    const float* q1b = (const float*)d_in[4];
    const float* k1w = (const float*)d_in[5];
    const float* k1b = (const float*)d_in[6];
    const float* v1w = (const float*)d_in[7];
    const float* v1b = (const float*)d_in[8];
    const float* e1w = (const float*)d_in[9];
    const float* s1w = (const float*)d_in[10];
    const float* s1b = (const float*)d_in[11];
    const float* q2w = (const float*)d_in[12];
    const float* q2b = (const float*)d_in[13];
    const float* k2w = (const float*)d_in[14];
    const float* k2b = (const float*)d_in[15];
    const float* v2w = (const float*)d_in[16];
    const float* v2b = (const float*)d_in[17];
    const float* e2w = (const float*)d_in[18];
    const float* s2w = (const float*)d_in[19];
    const float* s2b = (const float*)d_in[20];
    float* out = (float*)d_out;

    char* base = (char*)d_ws;
    size_t off = 0;
    auto alloc = [&](size_t nbytes) {
        size_t o = off; off += (nbytes + 255) & ~(size_t)255; return o;
    };
    const size_t xb_off   = alloc((size_t)MPAD * KDIM * 2);      // bf16 input
    const size_t wcat_off = alloc((size_t)4 * KDIM * KDIM * 2);  // fused weights (reused: Cpart)
    __hip_bfloat16* xb    = (__hip_bfloat16*)(base + xb_off);
    __hip_bfloat16* wcat  = (__hip_bfloat16*)(base + wcat_off);
    float*          Cpart = (float*)(base + wcat_off);            // alias (wcat dead after fused gemm)

    __hip_bfloat16* q1bb  = (__hip_bfloat16*)(base + alloc((size_t)MPAD * HC1 * 2));
    __hip_bfloat16* k1bb  = (__hip_bfloat16*)(base + alloc((size_t)MPAD * HC1 * 2));
    __hip_bfloat16* v1bb  = (__hip_bfloat16*)(base + alloc((size_t)MPAD * HC1 * 2));
    __hip_bfloat16* h1bf  = (__hip_bfloat16*)(base + alloc((size_t)MPAD * HC1 * 2));  // bf16 h1
    float*          bcat  = (float*)(base + alloc((size_t)4 * KDIM * 4));
    float*          P1    = (float*)(base + alloc((size_t)MPAD * 128 * 4));
    __hip_bfloat16* R1b   = (__hip_bfloat16*)(base + alloc((size_t)MPAD * 128 * 2));
    __hip_bfloat16* w1pp  = (__hip_bfloat16*)(base + alloc((size_t)128 * KDIM * 2));
    __hip_bfloat16* w1ppT = (__hip_bfloat16*)(base + alloc((size_t)KDIM * 128 * 2));
    __hip_bfloat16* w2t   = (__hip_bfloat16*)(base + alloc((size_t)256 * KDIM * 2));
    float*          b2    = (float*)(base + alloc(256 * 4));
    float*          qkvs2 = (float*)(base + alloc((size_t)MPAD * 256 * 4));
    float*          E2s   = (float*)(base + alloc((size_t)2112 * 64 * 4));
    int* deg    = (int*)(base + alloc((size_t)NN * 4));
    int* fill   = (int*)(base + alloc((size_t)NN * 4));
    int* rowptr = (int*)(base + alloc((size_t)(NN + 1) * 4));
    int* elist  = (int*)(base + alloc((size_t)NE * 4));

    // --- CSR build ---
    hipMemsetAsync(deg, 0, sizeof(int) * 2 * NN, stream);
    count_deg<<<(NE + 255) / 256, 256, 0, stream>>>(ei, deg);
    scan_kernel<<<1, 1024, 0, stream>>>(deg, rowptr);
    fill_csr<<<(NE + 255) / 256, 256, 0, stream>>>(ei, rowptr, fill, elist);
    sort_csr<<<(NN + 255) / 256, 256, 0, stream>>>(rowptr, elist);

    // --- merged prep (cvt_pad | transposes | misc | E2s) ---
    prep_kernel<<<27457, 256, 0, stream>>>(
        x, xb, q1w, k1w, v1w, s1w, wcat,
        q1b, k1b, v1b, s1b, e1w,
        q2w, k2w, v2w, s2w, q2b, k2b, v2b, s2b,
        bcat, w1pp, w1ppT, w2t, b2, ea, e2w, E2s);

    // --- fused layer-1 projections: 864-block 256^2 square-wave-tile ---
    gemm256sq_fused<<<864, 256, 0, stream>>>(xb, wcat, bcat, q1bb, k1bb, v1bb, h1bf);

    // --- P1 = q1 @ W1p (split-K 4) ---
    gemm_bf16<<<dim3(1, MPAD / 128, 4), 256, 0, stream>>>(q1bb, w1pp, nullptr, Cpart, nullptr,
                                                          MPAD, 128, KDIM, 0);
    reduce4<<<(MPAD * 128) / 256, 256, 0, stream>>>(Cpart, (size_t)MPAD * 128, nullptr, 0,
                                                    P1, MPAD * 128);

    // --- fused layer-1 attention (bf16 h1 rmw) ---
    node1_kernel<<<NN, 256, 0, stream>>>(q1bb, k1bb, v1bb, P1, ea, ei, rowptr, elist, h1bf, R1b);
    // h1 = relu(h1 + R1 @ W1pp)  -- bf16 in-place accumulate
    gemm_bf16<<<dim3(HC1 / 128, MPAD / 128), 256, 0, stream>>>(R1b, w1ppT, nullptr, nullptr,
                                                               h1bf, MPAD, HC1, 128, 16 | 4);

    // --- layer 2 projections (split-K 4) ---
    gemm_bf16<<<dim3(2, MPAD / 128, 4), 256, 0, stream>>>(h1bf, w2t, nullptr, Cpart, nullptr,
                                                          MPAD, 256, KDIM, 0);
    reduce4<<<(MPAD * 256) / 256, 256, 0, stream>>>(Cpart, (size_t)MPAD * 256, b2, 255,
                                                    qkvs2, MPAD * 256);

    // --- fused layer-2 attention ---
    node2_kernel<<<NN, 64, 0, stream>>>(qkvs2, E2s, ei, rowptr, elist, out);

    (void)in_sizes; (void)n_in; (void)out_size; (void)ws_size;
}

// Round 16
// 448.429 us; speedup vs baseline: 1.0792x; 1.0792x over previous
//
#include <hip/hip_runtime.h>
#include <hip/hip_bf16.h>
#include <cstdint>
#include <cstddef>

#define NN    6720     // nodes
#define MPAD  6912     // 27 * 256 = 54 * 128
#define NE    33600    // edges
#define KDIM  2048
#define HC1   2048
#define EAP   2100     // edge_attr tile period

typedef __attribute__((ext_vector_type(8))) short bhalf8;
typedef __attribute__((ext_vector_type(4))) short bhalf4;
typedef __attribute__((ext_vector_type(4))) float fx4;

__device__ __forceinline__ float bf2f(short s) {
    union { unsigned int u; float f; } c;
    c.u = ((unsigned int)(unsigned short)s) << 16;
    return c.f;
}

__device__ __forceinline__ void gload16(const __hip_bfloat16* g, void* lds)
{
    __builtin_amdgcn_global_load_lds(
        (const __attribute__((address_space(1))) unsigned int*)g,
        (__attribute__((address_space(3))) unsigned int*)lds,
        16, 0, 0);
}

#define CFENCE asm volatile("" ::: "memory")

// ------------------------------------------------------------------
// 256x128-tile 4-wave fused projection GEMM (r7/r14 kernel - best
// measured: 240µs / 44% MfmaUtil). Wave tile 128x64. BK=32, 3-deep
// LDS ring (72KB -> 2 blocks/CU), counted vmcnt(12/6/0), setprio,
// XOR swizzle both-sides, XCD-striped block map. bf16 epilogue.
// ------------------------------------------------------------------
__global__ __launch_bounds__(256, 2) void gemm256x128_fused(
    const __hip_bfloat16* __restrict__ A,
    const __hip_bfloat16* __restrict__ Bt,
    const float* __restrict__ bcat,
    __hip_bfloat16* __restrict__ oq,
    __hip_bfloat16* __restrict__ ok,
    __hip_bfloat16* __restrict__ ov,
    __hip_bfloat16* __restrict__ oh)
{
    __shared__ alignas(16) char Lds[73728];   // A ring 3x16KB @0 | B ring 3x8KB @49152

    const int bid = blockIdx.x;
    const int i0  = bid >> 3;
    const int bx  = (bid & 7) * 8 + (i0 & 7);   // N: 64 panels of 128
    const int by  = i0 >> 3;                    // M: 27 panels of 256

    const int tid  = threadIdx.x;
    const int w    = tid >> 6;        // 0..3
    const int lane = tid & 63;
    const int wm = w >> 1, wn = w & 1;    // 2x2 waves, wave tile 128x64
    const int rowA = by * 256;
    const int rowB = bx * 128;

    const int sug = ((lane & 3) ^ ((lane >> 3) & 3)) << 3;
    const __hip_bfloat16* Ag0 = A  + (size_t)(rowA + w * 64 + (lane >> 2)) * KDIM + sug;
    const __hip_bfloat16* Bg0 = Bt + (size_t)(rowB + w * 32 + (lane >> 2)) * KDIM + sug;

    const int rds = (((lane >> 4) ^ (((lane & 15) >> 1) & 3)) << 4);

    fx4 acc[8][4] = {};

#define STAGE(T)                                                          \
    { const int s_ = (T) % 3; const int k0_ = (T) * 32;                   \
      char* ab_ = Lds + s_ * 16384 + w * 4096;                            \
      char* bb_ = Lds + 49152 + s_ * 8192 + w * 2048;                     \
      gload16(Ag0 + k0_, ab_);                                            \
      gload16(Ag0 + k0_ + 16 * KDIM, ab_ + 1024);                         \
      gload16(Ag0 + k0_ + 32 * KDIM, ab_ + 2048);                         \
      gload16(Ag0 + k0_ + 48 * KDIM, ab_ + 3072);                         \
      gload16(Bg0 + k0_, bb_);                                            \
      gload16(Bg0 + k0_ + 16 * KDIM, bb_ + 1024); }

#define TILE(T, VM, DOSTAGE)                                              \
    { if (DOSTAGE) { STAGE((T) + 2); }                                    \
      asm volatile("s_waitcnt vmcnt(" VM ")" ::: "memory");               \
      __builtin_amdgcn_s_barrier(); CFENCE;                               \
      const int s_ = (T) % 3;                                             \
      const char* ap_ = Lds + s_ * 16384;                                 \
      const char* bp_ = Lds + 49152 + s_ * 8192;                          \
      bhalf8 af_[8], bf_[4];                                              \
      _Pragma("unroll")                                                   \
      for (int nj = 0; nj < 4; ++nj)                                      \
          bf_[nj] = *(const bhalf8*)(bp_ + (wn * 64 + nj * 16 + (lane & 15)) * 64 + rds); \
      _Pragma("unroll")                                                   \
      for (int mi = 0; mi < 8; ++mi)                                      \
          af_[mi] = *(const bhalf8*)(ap_ + (wm * 128 + mi * 16 + (lane & 15)) * 64 + rds); \
      __builtin_amdgcn_s_setprio(1);                                      \
      _Pragma("unroll")                                                   \
      for (int mi = 0; mi < 8; ++mi)                                      \
          _Pragma("unroll")                                               \
          for (int nj = 0; nj < 4; ++nj)                                  \
              acc[mi][nj] = __builtin_amdgcn_mfma_f32_16x16x32_bf16(      \
                  af_[mi], bf_[nj], acc[mi][nj], 0, 0, 0);                \
      __builtin_amdgcn_s_setprio(0); CFENCE;                              \
      __builtin_amdgcn_s_barrier(); CFENCE; }

    STAGE(0); STAGE(1);
    for (int t = 0; t < (KDIM / 32) - 2; ++t) {
        TILE(t, "12", 1);
    }
    TILE((KDIM / 32) - 2, "6", 0);
    TILE((KDIM / 32) - 1, "0", 0);

#undef TILE
#undef STAGE

    const int gcol = rowB + wn * 64;
    const int seg  = gcol >> 11;            // 0:q 1:k 2:v 3:skip
    const int lcol = gcol & 2047;
    float bv[4];
    #pragma unroll
    for (int nj = 0; nj < 4; ++nj) bv[nj] = bcat[gcol + nj * 16 + (lane & 15)];
    char* scr = Lds + w * 8704;             // wave-private 32 rows x 272B
    const int growA = rowA + wm * 128;
    __hip_bfloat16* dst = (seg == 0) ? oq : (seg == 1) ? ok : (seg == 2) ? ov : oh;

    #pragma unroll
    for (int c = 0; c < 4; ++c) {
        #pragma unroll
        for (int m2 = 0; m2 < 2; ++m2) {
            const int mi = c * 2 + m2;
            #pragma unroll
            for (int nj = 0; nj < 4; ++nj) {
                const int cl = nj * 16 + (lane & 15);
                #pragma unroll
                for (int i2 = 0; i2 < 4; ++i2) {
                    const int rl = m2 * 16 + ((lane >> 4) << 2) + i2;
                    *(float*)(scr + rl * 272 + cl * 4) = acc[mi][nj][i2] + bv[nj];
                }
            }
        }
        asm volatile("s_waitcnt lgkmcnt(0)" ::: "memory");
        CFENCE;
        const int rrow = (lane >> 4);
        const int u    = lane & 15;
        #pragma unroll
        for (int p = 0; p < 8; ++p) {
            const int row = p * 4 + rrow;
            const float4 f = *(const float4*)(scr + row * 272 + u * 16);
            bhalf4 tb;
            tb[0] = (short)__bfloat16_as_ushort(__float2bfloat16(f.x));
            tb[1] = (short)__bfloat16_as_ushort(__float2bfloat16(f.y));
            tb[2] = (short)__bfloat16_as_ushort(__float2bfloat16(f.z));
            tb[3] = (short)__bfloat16_as_ushort(__float2bfloat16(f.w));
            *(bhalf4*)&dst[(size_t)(growA + c * 32 + row) * 2048 + lcol + u * 4] = tb;
        }
        asm volatile("s_waitcnt lgkmcnt(0)" ::: "memory");
        CFENCE;
    }
}

// ------------------------------------------------------------------
// 128x128 bf16 MFMA GEMM (4 waves), optional split-K via blockIdx.z.
// flags: 1=+bias  2=+=C fp32 read  4=relu  8=skip C writeback
//        16=+=Cb bf16 read (in-place bf16 accumulate path)
// ------------------------------------------------------------------
__global__ __launch_bounds__(256) void gemm_bf16(
    const __hip_bfloat16* __restrict__ A,
    const __hip_bfloat16* __restrict__ Bt,
    const float* __restrict__ bias,
    float* __restrict__ C,
    __hip_bfloat16* __restrict__ Cb,
    int M, int N, int K, int flags)
{
    __shared__ alignas(16) __hip_bfloat16 Asm[128 * 64];
    __shared__ alignas(16) __hip_bfloat16 Bsm[128 * 64];
    const int tid  = threadIdx.x;
    const int w    = tid >> 6;
    const int lane = tid & 63;
    const int wr = w >> 1, wc = w & 1;
    const int rowA = blockIdx.y * 128;
    const int rowB = blockIdx.x * 128;
    const int klen = K / gridDim.z;
    const int kbeg = blockIdx.z * klen;

    const int srow = w * 32 + (lane >> 3);
    const int ug8  = ((lane & 7) ^ (lane >> 3)) << 3;
    const __hip_bfloat16* Ag = A  + (size_t)(rowA + srow) * K + ug8;
    const __hip_bfloat16* Bg = Bt + (size_t)(rowB + srow) * K + ug8;
    char* AsBase = (char*)Asm + w * 4096;
    char* BsBase = (char*)Bsm + w * 4096;

    fx4 acc[4][4] = {};

    const int fra = wr * 64 + (lane & 15);
    const int frb = wc * 64 + (lane & 15);
    const int kb  = (lane >> 4) << 4;
    const int swz = (lane & 7) << 4;

    for (int k0 = kbeg; k0 < kbeg + klen; k0 += 64) {
        __syncthreads();
        #pragma unroll
        for (int j = 0; j < 4; ++j) {
            gload16(Ag + (size_t)j * 8 * K + k0, AsBase + j * 1024);
            gload16(Bg + (size_t)j * 8 * K + k0, BsBase + j * 1024);
        }
        __syncthreads();
        #pragma unroll
        for (int kk = 0; kk < 2; ++kk) {
            const int cb = kk * 64 + kb;
            bhalf8 af[4], bfr[4];
            #pragma unroll
            for (int mi = 0; mi < 4; ++mi)
                af[mi] = *(const bhalf8*)((const char*)Asm + (fra + mi * 16) * 128 + (cb ^ swz));
            #pragma unroll
            for (int nj = 0; nj < 4; ++nj)
                bfr[nj] = *(const bhalf8*)((const char*)Bsm + (frb + nj * 16) * 128 + (cb ^ swz));
            #pragma unroll
            for (int mi = 0; mi < 4; ++mi)
                #pragma unroll
                for (int nj = 0; nj < 4; ++nj)
                    acc[mi][nj] = __builtin_amdgcn_mfma_f32_16x16x32_bf16(
                        af[mi], bfr[nj], acc[mi][nj], 0, 0, 0);
        }
    }

    float* Cz = C ? C + (size_t)blockIdx.z * ((size_t)M * N) : nullptr;
    #pragma unroll
    for (int nj = 0; nj < 4; ++nj) {
        const int ccol = rowB + wc * 64 + nj * 16 + (lane & 15);
        const float bv = (flags & 1) ? bias[ccol] : 0.f;
        #pragma unroll
        for (int mi = 0; mi < 4; ++mi) {
            const int crow0 = rowA + wr * 64 + mi * 16 + ((lane >> 4) << 2);
            #pragma unroll
            for (int i = 0; i < 4; ++i) {
                size_t idx = (size_t)(crow0 + i) * N + ccol;
                float v = acc[mi][nj][i] + bv;
                if (flags & 2)  v += Cz[idx];
                if (flags & 16) v += __bfloat162float(Cb[idx]);
                if (flags & 4)  v = fmaxf(v, 0.f);
                if (Cz && !(flags & 8)) Cz[idx] = v;
                if (Cb) Cb[idx] = __float2bfloat16(v);
            }
        }
    }
}

// dst[i] = sum_z parts[z*stride + i] (+ bias[i & colmask])
__global__ void reduce4(const float* __restrict__ parts, size_t stride,
                        const float* __restrict__ bias, int colmask,
                        float* __restrict__ dst, int n)
{
    int i = blockIdx.x * 256 + threadIdx.x;
    if (i >= n) return;
    float v = parts[i] + parts[stride + i] + parts[2 * stride + i] + parts[3 * stride + i];
    if (bias) v += bias[i & colmask];
    dst[i] = v;
}

// ------------------------------------------------------------------
// CSR build
// ------------------------------------------------------------------
__global__ void count_deg(const int* __restrict__ ei, int* __restrict__ deg)
{
    int e = blockIdx.x * 256 + threadIdx.x;
    if (e < NE) atomicAdd(&deg[ei[NE + e]], 1);
}

__global__ __launch_bounds__(1024) void scan_kernel(const int* __restrict__ deg,
                                                    int* __restrict__ rowptr)
{
    __shared__ int s[1024];
    const int t = threadIdx.x;
    const int base = t * 7;
    int loc[7];
    int sum = 0;
    #pragma unroll
    for (int i = 0; i < 7; ++i) {
        int idx = base + i;
        int v = (idx < NN) ? deg[idx] : 0;
        loc[i] = v; sum += v;
    }
    s[t] = sum;
    __syncthreads();
    for (int off = 1; off < 1024; off <<= 1) {
        int v = (t >= off) ? s[t - off] : 0;
        __syncthreads();
        s[t] += v;
        __syncthreads();
    }
    int running = s[t] - sum;
    #pragma unroll
    for (int i = 0; i < 7; ++i) {
        int idx = base + i;
        if (idx <= NN) rowptr[idx] = running;
        if (idx < NN) running += loc[i];
    }
}

__global__ void fill_csr(const int* __restrict__ ei, const int* __restrict__ rowptr,
                         int* __restrict__ fillctr, int* __restrict__ elist)
{
    int e = blockIdx.x * 256 + threadIdx.x;
    if (e >= NE) return;
    int d = ei[NE + e];
    int pos = atomicAdd(&fillctr[d], 1);
    elist[rowptr[d] + pos] = e;
}

__global__ void sort_csr(const int* __restrict__ rowptr, int* __restrict__ elist)
{
    int n = blockIdx.x * 256 + threadIdx.x;
    if (n >= NN) return;
    int s0 = rowptr[n], s1 = rowptr[n + 1];
    for (int i = s0 + 1; i < s1; ++i) {
        int v = elist[i];
        int j = i - 1;
        while (j >= s0 && elist[j] > v) { elist[j + 1] = elist[j]; --j; }
        elist[j + 1] = v;
    }
}

// ------------------------------------------------------------------
// merged prep kernel: roles by block range.
// ------------------------------------------------------------------
__global__ __launch_bounds__(256) void prep_kernel(
    const float* __restrict__ x, __hip_bfloat16* __restrict__ xb,
    const float* __restrict__ q1w, const float* __restrict__ k1w,
    const float* __restrict__ v1w, const float* __restrict__ s1w,
    __hip_bfloat16* __restrict__ wcat,
    const float* __restrict__ q1b, const float* __restrict__ k1b,
    const float* __restrict__ v1b, const float* __restrict__ s1b,
    const float* __restrict__ e1w,
    const float* __restrict__ q2w, const float* __restrict__ k2w,
    const float* __restrict__ v2w, const float* __restrict__ s2w,
    const float* __restrict__ q2bb, const float* __restrict__ k2bb,
    const float* __restrict__ v2bb, const float* __restrict__ s2bb,
    float* __restrict__ bcat, __hip_bfloat16* __restrict__ w1pp,
    __hip_bfloat16* __restrict__ w1ppT, __hip_bfloat16* __restrict__ w2t,
    float* __restrict__ b2,
    const float* __restrict__ ea, const float* __restrict__ e2w,
    float* __restrict__ E2s)
{
    __shared__ alignas(16) char plds[8448];
    const int bid = blockIdx.x;
    const int tid = threadIdx.x;

    if (bid < 6912) {                       // ---- cvt_pad (1 row/block) ----
        const int row = bid;
        const size_t base = (size_t)row * KDIM + tid * 8;
        float4 v0 = make_float4(0.f, 0.f, 0.f, 0.f), v1 = v0;
        if (row < NN) {
            v0 = *(const float4*)&x[base];
            v1 = *(const float4*)&x[base + 4];
        }
        bhalf8 o;
        o[0] = (short)__bfloat16_as_ushort(__float2bfloat16(v0.x));
        o[1] = (short)__bfloat16_as_ushort(__float2bfloat16(v0.y));
        o[2] = (short)__bfloat16_as_ushort(__float2bfloat16(v0.z));
        o[3] = (short)__bfloat16_as_ushort(__float2bfloat16(v0.w));
        o[4] = (short)__bfloat16_as_ushort(__float2bfloat16(v1.x));
        o[5] = (short)__bfloat16_as_ushort(__float2bfloat16(v1.y));
        o[6] = (short)__bfloat16_as_ushort(__float2bfloat16(v1.z));
        o[7] = (short)__bfloat16_as_ushort(__float2bfloat16(v1.w));
        *(bhalf8*)&xb[base] = o;
        return;
    }
    if (bid < 23296) {                      // ---- transpose_cvt4 ----
        const int idx = bid - 6912;
        const int z   = idx >> 12;          // 0..3
        const int rem = idx & 4095;
        const int byi = rem >> 6, bxi = rem & 63;
        const float* W = (z == 0) ? q1w : (z == 1) ? k1w : (z == 2) ? v1w : s1w;
        __hip_bfloat16* Bt = wcat + (size_t)z * KDIM * KDIM;
        float (*t)[33] = (float (*)[33])plds;
        const int kb = byi * 32, nb = bxi * 32;
        const int tx = tid & 31, ty = tid >> 5;
        #pragma unroll
        for (int i = 0; i < 32; i += 8)
            t[ty + i][tx] = W[(size_t)(kb + ty + i) * KDIM + nb + tx];
        __syncthreads();
        #pragma unroll
        for (int i = 0; i < 32; i += 8)
            Bt[(size_t)(nb + ty + i) * KDIM + kb + tx] = __float2bfloat16(t[tx][ty + i]);
        return;
    }
    if (bid < 27424) {                      // ---- build_misc ----
        int idx = (bid - 23296) * 256 + tid;
        if (idx < 8192) {
            int seg = idx >> 11, j = idx & 2047;
            const float* b = (seg == 0) ? q1b : (seg == 1) ? k1b : (seg == 2) ? v1b : s1b;
            bcat[idx] = b[j];
            return;
        }
        idx -= 8192;
        if (idx < 262144) {   // w1pp [128][2048]
            int p = idx >> 11, j = idx & 2047;
            float v = ((j >> 10) == (p >> 6)) ? e1w[(size_t)(p & 63) * KDIM + j] : 0.f;
            w1pp[idx] = __float2bfloat16(v);
            return;
        }
        idx -= 262144;
        if (idx < 262144) {   // w1ppT [2048][128]
            int n = idx >> 7, k = idx & 127;
            float v = ((n >> 10) == (k >> 6)) ? e1w[(size_t)(k & 63) * KDIM + n] : 0.f;
            w1ppT[idx] = __float2bfloat16(v);
            return;
        }
        idx -= 262144;        // w2t [256][2048] + b2
        int c = idx >> 11, d = idx & 2047;
        int g = c >> 6, j = c & 63;
        const float* w = (g == 0) ? q2w : (g == 1) ? k2w : (g == 2) ? v2w : s2w;
        w2t[idx] = __float2bfloat16(w[(size_t)d * 64 + j]);
        if (d == 0) {
            const float* b = (g == 0) ? q2bb : (g == 1) ? k2bb : (g == 2) ? v2bb : s2bb;
            b2[c] = b[j];
        }
        return;
    }
    // ---- E2s gemm: 64x64 tile, M=2112 N=64 K=64 ----
    {
        const int byi = bid - 27424;
        float (*As)[68] = (float (*)[68])plds;                 // 16x68 fp32
        float (*Bs)[64] = (float (*)[64])(plds + 4352);        // 16x64 fp32
        const int tx = tid & 15, ty = tid >> 4;
        const int arow = tid >> 2, acol = (tid & 3) << 2;
        const int brow = tid >> 4, bcol = (tid & 15) << 2;
        const float* Ag = ea + (size_t)(byi * 64 + arow) * 64 + acol;
        const float* Bg = e2w + (size_t)brow * 64 + bcol;
        float acc[4][4] = {};
        for (int k0 = 0; k0 < 64; k0 += 16) {
            const float4 av = *(const float4*)(Ag + k0);
            const float4 bv = *(const float4*)(Bg + (size_t)k0 * 64);
            __syncthreads();
            As[acol + 0][arow] = av.x;
            As[acol + 1][arow] = av.y;
            As[acol + 2][arow] = av.z;
            As[acol + 3][arow] = av.w;
            *(float4*)&Bs[brow][bcol] = bv;
            __syncthreads();
            #pragma unroll
            for (int kk = 0; kk < 16; ++kk) {
                const float4 a4 = *(const float4*)&As[kk][ty << 2];
                const float4 b4 = *(const float4*)&Bs[kk][tx << 2];
                const float a[4] = {a4.x, a4.y, a4.z, a4.w};
                const float b[4] = {b4.x, b4.y, b4.z, b4.w};
                #pragma unroll
                for (int i = 0; i < 4; ++i)
                    #pragma unroll
                    for (int j = 0; j < 4; ++j)
                        acc[i][j] += a[i] * b[j];
            }
        }
        const int crow = byi * 64 + (ty << 2);
        const int ccol = (tx << 2);
        #pragma unroll
        for (int i = 0; i < 4; ++i) {
            float4 v;
            v.x = acc[i][0]; v.y = acc[i][1]; v.z = acc[i][2]; v.w = acc[i][3];
            *(float4*)&E2s[(size_t)(crow + i) * 64 + ccol] = v;
        }
    }
}

// ------------------------------------------------------------------
// node1: fused alpha1 + softmax + R1 + V-aggregation. One block/node.
// q-row fragments and P1 values hoisted out of the edge loop (named
// registers, static indexing).
// ------------------------------------------------------------------
__global__ __launch_bounds__(256) void node1_kernel(
    const __hip_bfloat16* __restrict__ q1b, const __hip_bfloat16* __restrict__ k1b,
    const __hip_bfloat16* __restrict__ v1b,
    const float* __restrict__ P1, const float* __restrict__ ea,
    const int* __restrict__ ei, const int* __restrict__ rowptr,
    const int* __restrict__ elist,
    __hip_bfloat16* __restrict__ h1, __hip_bfloat16* __restrict__ R1)
{
    __shared__ int   s_src[256];
    __shared__ int   s_em[256];
    __shared__ float s_at[256][2];
    const int n = blockIdx.x;
    const int s0 = rowptr[n];
    const int deg = rowptr[n + 1] - s0;
    const int w = threadIdx.x >> 6, lane = threadIdx.x & 63;

    // hoisted loop invariants (static names, no arrays)
    const __hip_bfloat16* qbase = q1b + (size_t)n * HC1 + lane * 16;
    const bhalf8 qa0 = *(const bhalf8*)(qbase);
    const bhalf8 qc0 = *(const bhalf8*)(qbase + 8);
    const bhalf8 qa1 = *(const bhalf8*)(qbase + 1024);
    const bhalf8 qc1 = *(const bhalf8*)(qbase + 1024 + 8);
    const float  p10 = P1[(size_t)n * 128 + lane];
    const float  p11 = P1[(size_t)n * 128 + 64 + lane];

    for (int j = w; j < deg; j += 4) {
        const int e = elist[s0 + j];
        const int src = ei[e];
        const int em = e % EAP;
        if (lane == 0) { s_src[j] = src; s_em[j] = em; }
        const float eaj = ea[(size_t)em * 64 + lane];
        #pragma unroll
        for (int h = 0; h < 2; ++h) {
            const __hip_bfloat16* kh = k1b + (size_t)src * HC1 + h * 1024 + lane * 16;
            const bhalf8 qa = (h == 0) ? qa0 : qa1;
            const bhalf8 qc = (h == 0) ? qc0 : qc1;
            bhalf8 ka = *(const bhalf8*)kh, kc = *(const bhalf8*)(kh + 8);
            float s = 0.f;
            #pragma unroll
            for (int jj = 0; jj < 8; ++jj) s += bf2f(qa[jj]) * bf2f(ka[jj]);
            #pragma unroll
            for (int jj = 0; jj < 8; ++jj) s += bf2f(qc[jj]) * bf2f(kc[jj]);
            s += eaj * ((h == 0) ? p10 : p11);
            #pragma unroll
            for (int off = 32; off; off >>= 1) s += __shfl_xor(s, off);
            if (lane == 0) s_at[j][h] = s * 0.03125f;
        }
    }
    __syncthreads();

    if (threadIdx.x < 2) {
        const int h = threadIdx.x;
        float m = -1e30f;
        for (int j = 0; j < deg; ++j) m = fmaxf(m, s_at[j][h]);
        float sum = 0.f;
        for (int j = 0; j < deg; ++j) {
            float ex = __expf(s_at[j][h] - m);
            s_at[j][h] = ex; sum += ex;
        }
        float inv = 1.f / (sum + 1e-16f);
        for (int j = 0; j < deg; ++j) s_at[j][h] *= inv;
    }
    __syncthreads();

    if (threadIdx.x < 128) {
        const int h = threadIdx.x >> 6, jj = threadIdx.x & 63;
        float r = 0.f;
        for (int j = 0; j < deg; ++j)
            r += s_at[j][h] * ea[(size_t)s_em[j] * 64 + jj];
        R1[(size_t)n * 128 + threadIdx.x] = __float2bfloat16(r);
    }

    const int c0 = threadIdx.x * 8;
    const int h = c0 >> 10;
    float acc[8];
    const bhalf8 cur = *(const bhalf8*)&h1[(size_t)n * HC1 + c0];
    #pragma unroll
    for (int jj = 0; jj < 8; ++jj) acc[jj] = bf2f(cur[jj]);
    for (int j = 0; j < deg; ++j) {
        const float at = s_at[j][h];
        bhalf8 v = *(const bhalf8*)&v1b[(size_t)s_src[j] * HC1 + c0];
        #pragma unroll
        for (int jj = 0; jj < 8; ++jj) acc[jj] += at * bf2f(v[jj]);
    }
    bhalf8 o;
    #pragma unroll
    for (int jj = 0; jj < 8; ++jj)
        o[jj] = (short)__bfloat16_as_ushort(__float2bfloat16(acc[jj]));
    *(bhalf8*)&h1[(size_t)n * HC1 + c0] = o;
}

// ------------------------------------------------------------------
// node2: fused alpha2 + softmax + aggregation + relu. 1 wave/node.
// ------------------------------------------------------------------
__global__ __launch_bounds__(64) void node2_kernel(
    const float* __restrict__ qkvs2, const float* __restrict__ E2s,
    const int* __restrict__ ei, const int* __restrict__ rowptr,
    const int* __restrict__ elist, float* __restrict__ out)
{
    __shared__ float s_at[256];
    __shared__ int   s_src[256];
    __shared__ int   s_em[256];
    const int n = blockIdx.x;
    const int s0 = rowptr[n];
    const int deg = rowptr[n + 1] - s0;
    const int c = threadIdx.x;
    const float q = qkvs2[(size_t)n * 256 + c];

    for (int j = 0; j < deg; ++j) {
        const int e = elist[s0 + j];
        const int src = ei[e];
        const int em = e % EAP;
        float s = q * (qkvs2[(size_t)src * 256 + 64 + c] + E2s[(size_t)em * 64 + c]);
        #pragma unroll
        for (int off = 32; off; off >>= 1) s += __shfl_xor(s, off);
        if (c == 0) { s_at[j] = s * 0.125f; s_src[j] = src; s_em[j] = em; }
    }
    __syncthreads();
    float m = -1e30f;
    for (int j = 0; j < deg; ++j) m = fmaxf(m, s_at[j]);
    float sum = 0.f;
    for (int j = 0; j < deg; ++j) sum += __expf(s_at[j] - m);
    const float inv = 1.f / (sum + 1e-16f);

    float acc = qkvs2[(size_t)n * 256 + 192 + c];
    for (int j = 0; j < deg; ++j) {
        const float at = __expf(s_at[j] - m) * inv;
        acc += at * (qkvs2[(size_t)s_src[j] * 256 + 128 + c] + E2s[(size_t)s_em[j] * 64 + c]);
    }
    out[(size_t)n * 64 + c] = fmaxf(acc, 0.f);
}

// ------------------------------------------------------------------
extern "C" void kernel_launch(void* const* d_in, const int* in_sizes, int n_in,
                              void* d_out, int out_size, void* d_ws, size_t ws_size,
                              hipStream_t stream)
{
    const float* x   = (const float*)d_in[0];
    const int*   ei  = (const int*)d_in[1];
    const float* ea  = (const float*)d_in[2];
    const float* q1w = (const float*)d_in[3];
    const float* q1b = (const float*)d_in[4];
    const float* k1w = (const float*)d_in[5];
    const float* k1b = (const float*)d_in[6];
    const float* v1w = (const float*)d_in[7];
    const float* v1b = (const float*)d_in[8];
    const float* e1w = (const float*)d_in[9];
    const float* s1w = (const float*)d_in[10];
    const float* s1b = (const float*)d_in[11];
    const float* q2w = (const float*)d_in[12];
    const float* q2b = (const float*)d_in[13];
    const float* k2w = (const float*)d_in[14];
    const float* k2b = (const float*)d_in[15];
    const float* v2w = (const float*)d_in[16];
    const float* v2b = (const float*)d_in[17];
    const float* e2w = (const float*)d_in[18];
    const float* s2w = (const float*)d_in[19];
    const float* s2b = (const float*)d_in[20];
    float* out = (float*)d_out;

    char* base = (char*)d_ws;
    size_t off = 0;
    auto alloc = [&](size_t nbytes) {
        size_t o = off; off += (nbytes + 255) & ~(size_t)255; return o;
    };
    const size_t xb_off   = alloc((size_t)MPAD * KDIM * 2);      // bf16 input
    const size_t wcat_off = alloc((size_t)4 * KDIM * KDIM * 2);  // fused weights (reused: Cpart)
    __hip_bfloat16* xb    = (__hip_bfloat16*)(base + xb_off);
    __hip_bfloat16* wcat  = (__hip_bfloat16*)(base + wcat_off);
    float*          Cpart = (float*)(base + wcat_off);            // alias (wcat dead after fused gemm)

    __hip_bfloat16* q1bb  = (__hip_bfloat16*)(base + alloc((size_t)MPAD * HC1 * 2));
    __hip_bfloat16* k1bb  = (__hip_bfloat16*)(base + alloc((size_t)MPAD * HC1 * 2));
    __hip_bfloat16* v1bb  = (__hip_bfloat16*)(base + alloc((size_t)MPAD * HC1 * 2));
    __hip_bfloat16* h1bf  = (__hip_bfloat16*)(base + alloc((size_t)MPAD * HC1 * 2));  // bf16 h1
    float*          bcat  = (float*)(base + alloc((size_t)4 * KDIM * 4));
    float*          P1    = (float*)(base + alloc((size_t)MPAD * 128 * 4));
    __hip_bfloat16* R1b   = (__hip_bfloat16*)(base + alloc((size_t)MPAD * 128 * 2));
    __hip_bfloat16* w1pp  = (__hip_bfloat16*)(base + alloc((size_t)128 * KDIM * 2));
    __hip_bfloat16* w1ppT = (__hip_bfloat16*)(base + alloc((size_t)KDIM * 128 * 2));
    __hip_bfloat16* w2t   = (__hip_bfloat16*)(base + alloc((size_t)256 * KDIM * 2));
    float*          b2    = (float*)(base + alloc(256 * 4));
    float*          qkvs2 = (float*)(base + alloc((size_t)MPAD * 256 * 4));
    float*          E2s   = (float*)(base + alloc((size_t)2112 * 64 * 4));
    int* deg    = (int*)(base + alloc((size_t)NN * 4));
    int* fill   = (int*)(base + alloc((size_t)NN * 4));
    int* rowptr = (int*)(base + alloc((size_t)(NN + 1) * 4));
    int* elist  = (int*)(base + alloc((size_t)NE * 4));

    // --- CSR build ---
    hipMemsetAsync(deg, 0, sizeof(int) * 2 * NN, stream);
    count_deg<<<(NE + 255) / 256, 256, 0, stream>>>(ei, deg);
    scan_kernel<<<1, 1024, 0, stream>>>(deg, rowptr);
    fill_csr<<<(NE + 255) / 256, 256, 0, stream>>>(ei, rowptr, fill, elist);
    sort_csr<<<(NN + 255) / 256, 256, 0, stream>>>(rowptr, elist);

    // --- merged prep (cvt_pad | transposes | misc | E2s) ---
    prep_kernel<<<27457, 256, 0, stream>>>(
        x, xb, q1w, k1w, v1w, s1w, wcat,
        q1b, k1b, v1b, s1b, e1w,
        q2w, k2w, v2w, s2w, q2b, k2b, v2b, s2b,
        bcat, w1pp, w1ppT, w2t, b2, ea, e2w, E2s);

    // --- fused layer-1 projections (q,k,v,skip all bf16) ---
    gemm256x128_fused<<<1728, 256, 0, stream>>>(xb, wcat, bcat, q1bb, k1bb, v1bb, h1bf);

    // --- P1 = q1 @ W1p (split-K 4) ---
    gemm_bf16<<<dim3(1, MPAD / 128, 4), 256, 0, stream>>>(q1bb, w1pp, nullptr, Cpart, nullptr,
                                                          MPAD, 128, KDIM, 0);
    reduce4<<<(MPAD * 128) / 256, 256, 0, stream>>>(Cpart, (size_t)MPAD * 128, nullptr, 0,
                                                    P1, MPAD * 128);

    // --- fused layer-1 attention (bf16 h1 rmw) ---
    node1_kernel<<<NN, 256, 0, stream>>>(q1bb, k1bb, v1bb, P1, ea, ei, rowptr, elist, h1bf, R1b);
    // h1 = relu(h1 + R1 @ W1pp)  -- bf16 in-place accumulate
    gemm_bf16<<<dim3(HC1 / 128, MPAD / 128), 256, 0, stream>>>(R1b, w1ppT, nullptr, nullptr,
                                                               h1bf, MPAD, HC1, 128, 16 | 4);

    // --- layer 2 projections (split-K 4) ---
    gemm_bf16<<<dim3(2, MPAD / 128, 4), 256, 0, stream>>>(h1bf, w2t, nullptr, Cpart, nullptr,
                                                          MPAD, 256, KDIM, 0);
    reduce4<<<(MPAD * 256) / 256, 256, 0, stream>>>(Cpart, (size_t)MPAD * 256, b2, 255,
                                                    qkvs2, MPAD * 256);

    // --- fused layer-2 attention ---
    node2_kernel<<<NN, 64, 0, stream>>>(qkvs2, E2s, ei, rowptr, elist, out);

    (void)in_sizes; (void)n_in; (void)out_size; (void)ws_size;
}